// Round 1
// baseline (115.951 us; speedup 1.0000x reference)
//
#include <hip/hip_runtime.h>

typedef float f32x4 __attribute__((ext_vector_type(4)));
typedef short s16x8 __attribute__((ext_vector_type(8)));
typedef short s16x4 __attribute__((ext_vector_type(4)));

#define NT 48
#define NE 48
#define NB 32
#define VS 512
// C layout in ws: rows 0..1535 = ta[t*32+b][h] (b1 folded in), rows 1536..3071 = eb[n*32+b][h]

__device__ __forceinline__ unsigned short f2bf(float f) {
  union { float f; unsigned u; } v; v.f = f;
  unsigned u = v.u;
  unsigned r = u + 0x7FFFu + ((u >> 16) & 1u);   // RNE
  return (unsigned short)(r >> 16);
}

__device__ __forceinline__ float tanhf_fast(float x) {
  // tanh(x) = 1 - 2/(exp(2x)+1); exp via v_exp_f32, rcp via v_rcp_f32.
  float e = __expf(x * 2.0f);
  return 1.0f - 2.0f * __builtin_amdgcn_rcpf(e + 1.0f);
}

// ---------------- Kernel 1: C = [targets; embeddings] · W1(a|b)^T (+b1 on ta rows) ----------------
// NT-GEMM, M=3072 N=512 K=512, bf16 MFMA 16x16x32, tiles 64x64x32.
__global__ __launch_bounds__(256) void k_gemm(
    const float* __restrict__ targets, const float* __restrict__ embeddings,
    const float* __restrict__ W1, const float* __restrict__ b1,
    float* __restrict__ C) {
  __shared__ short sa[64][40];   // row +8 pad (16B) to spread banks
  __shared__ short sb[64][40];

  const int bid = blockIdx.x;
  const int mt = bid >> 3;            // 0..47
  const int ht = bid & 7;             // 0..7
  const int m0 = mt * 64, h0 = ht * 64;
  const bool is_ta = (m0 < 1536);
  const float* Abase = is_ta ? (targets + (size_t)m0 * VS)
                             : (embeddings + (size_t)(m0 - 1536) * VS);
  const float* Bbase = W1 + (size_t)h0 * 1024 + (is_ta ? 0 : 512);

  const int tid = threadIdx.x;
  const int lane = tid & 63, w = tid >> 6;
  const int q = lane >> 4, i = lane & 15;

  f32x4 acc[4] = {{0.f,0.f,0.f,0.f},{0.f,0.f,0.f,0.f},{0.f,0.f,0.f,0.f},{0.f,0.f,0.f,0.f}};

  for (int kt = 0; kt < 16; ++kt) {
    const int k0 = kt * 32;
    if (kt) __syncthreads();
    // stage 64x32 A-tile + 64x32 B-tile, fp32->bf16, 4 float4 per thread
#pragma unroll
    for (int r = 0; r < 4; ++r) {
      int f = r * 256 + tid;          // 0..1023
      int g = f & 511;
      int row = g >> 3;               // 0..63
      int col4 = (g & 7) << 2;        // 0,4,..,28
      const float* src = (f < 512) ? (Abase + (size_t)row * VS + k0 + col4)
                                   : (Bbase + (size_t)row * 1024 + k0 + col4);
      f32x4 v = *(const f32x4*)src;
      s16x4 o;
#pragma unroll
      for (int u = 0; u < 4; ++u) o[u] = (short)f2bf(v[u]);
      short* dst = (f < 512) ? &sa[row][col4] : &sb[row][col4];
      *(s16x4*)dst = o;
    }
    __syncthreads();
    // wave w computes rows [16w,16w+16) x 64 cols: 4 MFMA per K-step of 32
    s16x8 av = *(const s16x8*)&sa[16 * w + i][q * 8];
#pragma unroll
    for (int c = 0; c < 4; ++c) {
      s16x8 bv = *(const s16x8*)&sb[c * 16 + i][q * 8];
      acc[c] = __builtin_amdgcn_mfma_f32_16x16x32_bf16(av, bv, acc[c], 0, 0, 0);
    }
  }

  // epilogue: D[row=q*4+r][col=lane&15] per verified C/D mapping
#pragma unroll
  for (int c = 0; c < 4; ++c) {
#pragma unroll
    for (int r = 0; r < 4; ++r) {
      int ml = 16 * w + q * 4 + r;
      int hl = c * 16 + i;
      int m = m0 + ml, h = h0 + hl;
      float v = acc[c][r];
      if (is_ta) v += b1[h];
      C[(size_t)m * VS + h] = v;
    }
  }
}

// ---------------- Kernel 2: out[t,n,b] = sum_h tanh(ta+eb)*W2[h] + b2 ----------------
// Grid: 3x3 output tiles (16x16) x 32 b = 288 blocks. 256 threads:
// wave = h-quarter, thread = 2x2 output micro-tile. h staged in 2 chunks of 256.
__global__ __launch_bounds__(256) void k_fuse(
    const float* __restrict__ C, const float* __restrict__ W2,
    const float* __restrict__ b2, float* __restrict__ out) {
  __shared__ float sta[16][260];   // stride 260 (=4 mod 32): conflict-free f32x4 reads
  __shared__ float seb[16][260];
  __shared__ float w2c[512];
  __shared__ float red[4][16][17];

  const int bid = blockIdx.x;
  const int b = bid / 9;
  const int r9 = bid % 9;
  const int t0 = (r9 / 3) * 16, n0 = (r9 % 3) * 16;

  const int tid = threadIdx.x;
  const int lane = tid & 63, hq = tid >> 6;    // wave id = h quarter
  const int i0 = lane & 7, j0 = (lane >> 3) & 7;

  if (tid < 128) *(f32x4*)&w2c[tid * 4] = *(const f32x4*)&W2[tid * 4];

  float a00 = 0.f, a01 = 0.f, a10 = 0.f, a11 = 0.f;

  for (int chunk = 0; chunk < 2; ++chunk) {
    __syncthreads();   // staging buffers free (covers w2c load on chunk 0 too)
    // stage 16x256 of ta and of eb: 8 float4 per thread, fully coalesced
#pragma unroll
    for (int r = 0; r < 8; ++r) {
      int f = r * 256 + tid;            // 0..2047
      int g = f & 1023;
      int row = g >> 6;                 // 0..15
      int col4 = (g & 63) << 2;         // 0..252
      int m = (f < 1024) ? ((t0 + row) * NB + b)
                         : (1536 + (n0 + row) * NB + b);
      f32x4 v = *(const f32x4*)&C[(size_t)m * VS + chunk * 256 + col4];
      float* dst = (f < 1024) ? &sta[row][col4] : &seb[row][col4];
      *(f32x4*)dst = v;
    }
    __syncthreads();

    const int hbase = hq * 64;
#pragma unroll 4
    for (int it = 0; it < 16; ++it) {
      int h = hbase + it * 4;
      f32x4 ta0 = *(const f32x4*)&sta[i0][h];
      f32x4 ta1 = *(const f32x4*)&sta[i0 + 8][h];
      f32x4 eb0 = *(const f32x4*)&seb[j0][h];
      f32x4 eb1 = *(const f32x4*)&seb[j0 + 8][h];
      f32x4 w4  = *(const f32x4*)&w2c[chunk * 256 + h];
#pragma unroll
      for (int u = 0; u < 4; ++u) {
        float ww = w4[u];
        a00 += tanhf_fast(ta0[u] + eb0[u]) * ww;
        a01 += tanhf_fast(ta0[u] + eb1[u]) * ww;
        a10 += tanhf_fast(ta1[u] + eb0[u]) * ww;
        a11 += tanhf_fast(ta1[u] + eb1[u]) * ww;
      }
    }
  }

  // cross-wave (h-quarter) reduction
  red[hq][i0][j0]         = a00;
  red[hq][i0][j0 + 8]     = a01;
  red[hq][i0 + 8][j0]     = a10;
  red[hq][i0 + 8][j0 + 8] = a11;
  __syncthreads();
  {
    int tl = tid & 15, nl = tid >> 4;
    float s = red[0][tl][nl] + red[1][tl][nl] + red[2][tl][nl] + red[3][tl][nl] + b2[0];
    out[((size_t)(t0 + tl) * NE + (n0 + nl)) * NB + b] = s;
  }
}

extern "C" void kernel_launch(void* const* d_in, const int* in_sizes, int n_in,
                              void* d_out, int out_size, void* d_ws, size_t ws_size,
                              hipStream_t stream) {
  (void)in_sizes; (void)n_in; (void)out_size; (void)ws_size;
  const float* targets    = (const float*)d_in[0];
  const float* embeddings = (const float*)d_in[1];
  const float* W1         = (const float*)d_in[2];
  const float* b1         = (const float*)d_in[3];
  const float* W2         = (const float*)d_in[4];
  const float* b2         = (const float*)d_in[5];
  float* out = (float*)d_out;
  float* C   = (float*)d_ws;   // 3072*512 fp32 = 6 MB scratch

  k_gemm<<<dim3(384), dim3(256), 0, stream>>>(targets, embeddings, W1, b1, C);
  k_fuse<<<dim3(288), dim3(256), 0, stream>>>(C, W2, b2, out);
}

// Round 2
// 103.861 us; speedup vs baseline: 1.1164x; 1.1164x over previous
//
#include <hip/hip_runtime.h>
#include <hip/hip_bf16.h>

typedef float f32x4 __attribute__((ext_vector_type(4)));
typedef short s16x8 __attribute__((ext_vector_type(8)));

#define NT 48
#define NE 48
#define NB 32
#define VS 512
#define NOUT (NT * NE * NB)
#define CX_OFF (3072 * 512)   // ws offset (floats) of Swb_q[4]

// ---------------- Kernel 1 ----------------
// C rows 0..1535  = exp(2*(ta+b1)) for m = t*32+b
// C rows 1536..3071 = exp(2*eb)    for m = 1536 + n*32+b
// Also: zero d_out; block 0 computes Swb_q[q] = b2/4 + sum_{h in quarter q} W2[h].
__global__ __launch_bounds__(256) void k_gemm(
    const float* __restrict__ targets, const float* __restrict__ embeddings,
    const float* __restrict__ W1, const float* __restrict__ b1,
    const float* __restrict__ W2, const float* __restrict__ b2,
    float* __restrict__ C, float* __restrict__ out) {
  __shared__ short sa[64][40];
  __shared__ short sb[64][40];

  const int bid = blockIdx.x;
  const int tid = threadIdx.x;

  // zero the output (k_fuse accumulates atomically); 384*256 = 98304 >= 73728
  {
    int zi = bid * 256 + tid;
    if (zi < NOUT) out[zi] = 0.0f;
  }
  // per-quarter W2 sums (+ b2/4), block 0 wave 0
  if (bid == 0 && tid < 64) {
#pragma unroll
    for (int q = 0; q < 4; ++q) {
      float s = W2[q * 128 + tid] + W2[q * 128 + 64 + tid];
#pragma unroll
      for (int off = 32; off; off >>= 1) s += __shfl_xor(s, off, 64);
      if (tid == 0) C[CX_OFF + q] = 0.25f * b2[0] + s;
    }
  }

  const int mt = bid >> 3;            // 0..47
  const int ht = bid & 7;             // 0..7
  const int m0 = mt * 64, h0 = ht * 64;
  const bool is_ta = (m0 < 1536);
  const float* Abase = is_ta ? (targets + (size_t)m0 * VS)
                             : (embeddings + (size_t)(m0 - 1536) * VS);
  const float* Bbase = W1 + (size_t)h0 * 1024 + (is_ta ? 0 : 512);

  const int lane = tid & 63, w = tid >> 6;
  const int q = lane >> 4, i = lane & 15;

  f32x4 acc[4] = {{0.f,0.f,0.f,0.f},{0.f,0.f,0.f,0.f},{0.f,0.f,0.f,0.f},{0.f,0.f,0.f,0.f}};

  for (int kt = 0; kt < 16; ++kt) {
    const int k0 = kt * 32;
    if (kt) __syncthreads();
    // stage 64x32 A-tile + 64x32 B-tile, fp32->bf16 packed cvt
#pragma unroll
    for (int r = 0; r < 4; ++r) {
      int f = r * 256 + tid;          // 0..1023
      int g = f & 511;
      int row = g >> 3;               // 0..63
      int col4 = (g & 7) << 2;        // 0,4,..,28
      const float* src = (f < 512) ? (Abase + (size_t)row * VS + k0 + col4)
                                   : (Bbase + (size_t)row * 1024 + k0 + col4);
      f32x4 v = *(const f32x4*)src;
      union { __hip_bfloat162 h2; unsigned u; } c0, c1;
      c0.h2 = __float22bfloat162_rn(float2{v[0], v[1]});
      c1.h2 = __float22bfloat162_rn(float2{v[2], v[3]});
      uint2 o; o.x = c0.u; o.y = c1.u;
      short* dst = (f < 512) ? &sa[row][col4] : &sb[row][col4];
      *(uint2*)dst = o;
    }
    __syncthreads();
    s16x8 av = *(const s16x8*)&sa[16 * w + i][q * 8];
#pragma unroll
    for (int c = 0; c < 4; ++c) {
      s16x8 bv = *(const s16x8*)&sb[c * 16 + i][q * 8];
      acc[c] = __builtin_amdgcn_mfma_f32_16x16x32_bf16(av, bv, acc[c], 0, 0, 0);
    }
  }

  // epilogue: D[row=q*4+r][col=lane&15]; store exp(2*(v [+ b1]))
#pragma unroll
  for (int c = 0; c < 4; ++c) {
#pragma unroll
    for (int r = 0; r < 4; ++r) {
      int ml = 16 * w + q * 4 + r;
      int hl = c * 16 + i;
      int m = m0 + ml, h = h0 + hl;
      float v = acc[c][r];
      if (is_ta) v += b1[h];
      C[(size_t)m * VS + h] = __expf(v + v);
    }
  }
}

// ---------------- Kernel 2 ----------------
// out[t,n,b] += Swb_q[hq] - 2 * sum_{h in quarter} W2[h] / (Et*En + 1)
// Grid: 3x3 tiles (16x16) x 4 h-quarters x 32 b = 1152 blocks, 512 threads.
__global__ __launch_bounds__(512) void k_fuse(
    const float* __restrict__ C, const float* __restrict__ W2,
    float* __restrict__ out) {
  __shared__ float sta[16][132];   // stride 132 (=4 mod 32): conflict-free b128
  __shared__ float seb[16][132];
  __shared__ float w2c[128];
  __shared__ float red[8][16][17];

  const int bid = blockIdx.x;
  const int b = bid & 31;
  const int r5 = bid >> 5;          // 0..35
  const int hq = r5 & 3;
  const int r2 = r5 >> 2;           // 0..8
  const int t0 = (r2 / 3) * 16, n0 = (r2 % 3) * 16;

  const int tid = threadIdx.x;

  // stage 16x128 of Et and En (already exp'd in k_gemm)
#pragma unroll
  for (int rr = 0; rr < 2; ++rr) {
    int f = rr * 512 + tid;          // 0..1023
    int g = f & 511;
    int row = g >> 5;                // 0..15
    int col4 = (g & 31) << 2;        // 0..124
    int m = (f < 512) ? ((t0 + row) * NB + b)
                      : (1536 + (n0 + row) * NB + b);
    f32x4 v = *(const f32x4*)&C[(size_t)m * VS + hq * 128 + col4];
    float* dst = (f < 512) ? &sta[row][col4] : &seb[row][col4];
    *(f32x4*)dst = v;
  }
  if (tid < 32) *(f32x4*)&w2c[tid * 4] = *(const f32x4*)&W2[hq * 128 + tid * 4];
  __syncthreads();

  const int w = tid >> 6, lane = tid & 63;
  const int i0 = lane & 7, j0 = (lane >> 3) & 7;
  const int hb = w * 16;

  float a00 = 0.f, a01 = 0.f, a10 = 0.f, a11 = 0.f;
#pragma unroll
  for (int it = 0; it < 4; ++it) {
    int h = hb + it * 4;
    f32x4 et0 = *(const f32x4*)&sta[i0][h];
    f32x4 et1 = *(const f32x4*)&sta[i0 + 8][h];
    f32x4 en0 = *(const f32x4*)&seb[j0][h];
    f32x4 en1 = *(const f32x4*)&seb[j0 + 8][h];
    f32x4 w4  = *(const f32x4*)&w2c[h];
#pragma unroll
    for (int u = 0; u < 4; ++u) {
      float r00 = __builtin_amdgcn_rcpf(et0[u] * en0[u] + 1.0f);
      float r01 = __builtin_amdgcn_rcpf(et0[u] * en1[u] + 1.0f);
      float r10 = __builtin_amdgcn_rcpf(et1[u] * en0[u] + 1.0f);
      float r11 = __builtin_amdgcn_rcpf(et1[u] * en1[u] + 1.0f);
      float ww = w4[u];
      a00 += ww * r00; a01 += ww * r01; a10 += ww * r10; a11 += ww * r11;
    }
  }

  red[w][i0][j0]         = a00;
  red[w][i0][j0 + 8]     = a01;
  red[w][i0 + 8][j0]     = a10;
  red[w][i0 + 8][j0 + 8] = a11;
  __syncthreads();

  if (tid < 256) {
    int tl = tid & 15, nl = tid >> 4;
    float s = 0.f;
#pragma unroll
    for (int ww = 0; ww < 8; ++ww) s += red[ww][tl][nl];
    float val = C[CX_OFF + hq] - 2.0f * s;
    atomicAdd(&out[((size_t)(t0 + tl) * NE + (n0 + nl)) * NB + b], val);
  }
}

extern "C" void kernel_launch(void* const* d_in, const int* in_sizes, int n_in,
                              void* d_out, int out_size, void* d_ws, size_t ws_size,
                              hipStream_t stream) {
  (void)in_sizes; (void)n_in; (void)out_size; (void)ws_size;
  const float* targets    = (const float*)d_in[0];
  const float* embeddings = (const float*)d_in[1];
  const float* W1         = (const float*)d_in[2];
  const float* b1         = (const float*)d_in[3];
  const float* W2         = (const float*)d_in[4];
  const float* b2         = (const float*)d_in[5];
  float* out = (float*)d_out;
  float* C   = (float*)d_ws;   // 3072*512 fp32 + 4 floats of Swb_q

  k_gemm<<<dim3(384), dim3(256), 0, stream>>>(targets, embeddings, W1, b1, W2, b2, C, out);
  k_fuse<<<dim3(1152), dim3(512), 0, stream>>>(C, W2, out);
}

// Round 3
// 101.042 us; speedup vs baseline: 1.1476x; 1.0279x over previous
//
#include <hip/hip_runtime.h>
#include <hip/hip_bf16.h>

typedef float f32x4 __attribute__((ext_vector_type(4)));
typedef short s16x8 __attribute__((ext_vector_type(8)));

#define NT 48
#define NE 48
#define NB 32
#define VS 512
#define NOUT (NT * NE * NB)
#define CX_OFF (3072 * 512)   // ws offset (floats) of Swb_q[4]

// ---------------- Kernel 1 ----------------
// C rows 0..1535    = exp(2*(ta+b1)) for m = t*32+b
// C rows 1536..3071 = exp(2*eb)      for m = 1536 + n*32+b
// Also: zero d_out; block 0 computes Swb_q[q] = b2/4 + sum_{h in quarter q} W2[h].
// Double-buffered LDS staging, one barrier per K-iteration.
__global__ __launch_bounds__(256) void k_gemm(
    const float* __restrict__ targets, const float* __restrict__ embeddings,
    const float* __restrict__ W1, const float* __restrict__ b1,
    const float* __restrict__ W2, const float* __restrict__ b2,
    float* __restrict__ C, float* __restrict__ out) {
  __shared__ short sa[2][64][40];
  __shared__ short sb[2][64][40];

  const int bid = blockIdx.x;
  const int tid = threadIdx.x;

  // zero the output (k_fuse accumulates atomically); 384*256 = 98304 >= 73728
  {
    int zi = bid * 256 + tid;
    if (zi < NOUT) out[zi] = 0.0f;
  }
  // per-quarter W2 sums (+ b2/4), block 0 wave 0
  if (bid == 0 && tid < 64) {
#pragma unroll
    for (int q = 0; q < 4; ++q) {
      float s = W2[q * 128 + tid] + W2[q * 128 + 64 + tid];
#pragma unroll
      for (int off = 32; off; off >>= 1) s += __shfl_xor(s, off, 64);
      if (tid == 0) C[CX_OFF + q] = 0.25f * b2[0] + s;
    }
  }

  const int mt = bid >> 3;            // 0..47
  const int ht = bid & 7;             // 0..7
  const int m0 = mt * 64, h0 = ht * 64;
  const bool is_ta = (m0 < 1536);
  const float* Abase = is_ta ? (targets + (size_t)m0 * VS)
                             : (embeddings + (size_t)(m0 - 1536) * VS);
  const float* Bbase = W1 + (size_t)h0 * 1024 + (is_ta ? 0 : 512);

  const int lane = tid & 63, w = tid >> 6;
  const int q = lane >> 4, i = lane & 15;

  // per-thread staging addresses (fixed across kt except the k offset)
  const float* gsrc[4];
  int loff[4];
  bool isA[4];
#pragma unroll
  for (int r = 0; r < 4; ++r) {
    int f = r * 256 + tid;            // 0..1023
    int g = f & 511;
    int row = g >> 3;                 // 0..63
    int col4 = (g & 7) << 2;          // 0,4,..,28
    isA[r] = (f < 512);
    gsrc[r] = isA[r] ? (Abase + (size_t)row * VS + col4)
                     : (Bbase + (size_t)row * 1024 + col4);
    loff[r] = row * 40 + col4;
  }

  f32x4 acc[4] = {{0.f,0.f,0.f,0.f},{0.f,0.f,0.f,0.f},{0.f,0.f,0.f,0.f},{0.f,0.f,0.f,0.f}};

  f32x4 v[4];
#pragma unroll
  for (int r = 0; r < 4; ++r) v[r] = *(const f32x4*)(gsrc[r]);

  for (int kt = 0; kt < 16; ++kt) {
    const int p = kt & 1;
    // cvt + write tile kt into buffer p
#pragma unroll
    for (int r = 0; r < 4; ++r) {
      union { __hip_bfloat162 h2; unsigned u; } c0, c1;
      c0.h2 = __float22bfloat162_rn(float2{v[r][0], v[r][1]});
      c1.h2 = __float22bfloat162_rn(float2{v[r][2], v[r][3]});
      uint2 o; o.x = c0.u; o.y = c1.u;
      short* base = isA[r] ? &sa[p][0][0] : &sb[p][0][0];
      *(uint2*)(base + loff[r]) = o;
    }
    __syncthreads();
    // prefetch tile kt+1 (latency hidden under the MFMAs below)
    if (kt < 15) {
      const int k1 = (kt + 1) * 32;
#pragma unroll
      for (int r = 0; r < 4; ++r) v[r] = *(const f32x4*)(gsrc[r] + k1);
    }
    // consume buffer p
    s16x8 av = *(const s16x8*)&sa[p][16 * w + i][q * 8];
#pragma unroll
    for (int c = 0; c < 4; ++c) {
      s16x8 bv = *(const s16x8*)&sb[p][c * 16 + i][q * 8];
      acc[c] = __builtin_amdgcn_mfma_f32_16x16x32_bf16(av, bv, acc[c], 0, 0, 0);
    }
  }

  // epilogue: D[row=q*4+r][col=lane&15]; store exp(2*(v [+ b1]))
#pragma unroll
  for (int c = 0; c < 4; ++c) {
#pragma unroll
    for (int r = 0; r < 4; ++r) {
      int ml = 16 * w + q * 4 + r;
      int hl = c * 16 + i;
      int m = m0 + ml, h = h0 + hl;
      float vv = acc[c][r];
      if (is_ta) vv += b1[h];
      C[(size_t)m * VS + h] = __expf(vv + vv);
    }
  }
}

// ---------------- Kernel 2 ----------------
// out[t,n,b] += Swb_q[hq] - 2 * sum_{h in quarter} W2[h] / (Et*En + 1)
// Grid: 3x3 tiles (16x16) x 4 h-quarters x 32 b = 1152 blocks, 512 threads.
__global__ __launch_bounds__(512) void k_fuse(
    const float* __restrict__ C, const float* __restrict__ W2,
    float* __restrict__ out) {
  __shared__ float sta[16][132];   // stride 132 (=4 mod 32): conflict-free b128
  __shared__ float seb[16][132];
  __shared__ float w2c[128];
  __shared__ float red[8][16][17];

  const int bid = blockIdx.x;
  const int b = bid & 31;
  const int r5 = bid >> 5;          // 0..35
  const int hq = r5 & 3;
  const int r2 = r5 >> 2;           // 0..8
  const int t0 = (r2 / 3) * 16, n0 = (r2 % 3) * 16;

  const int tid = threadIdx.x;

  // stage 16x128 of Et and En (already exp'd in k_gemm)
#pragma unroll
  for (int rr = 0; rr < 2; ++rr) {
    int f = rr * 512 + tid;          // 0..1023
    int g = f & 511;
    int row = g >> 5;                // 0..15
    int col4 = (g & 31) << 2;        // 0..124
    int m = (f < 512) ? ((t0 + row) * NB + b)
                      : (1536 + (n0 + row) * NB + b);
    f32x4 v = *(const f32x4*)&C[(size_t)m * VS + hq * 128 + col4];
    float* dst = (f < 512) ? &sta[row][col4] : &seb[row][col4];
    *(f32x4*)dst = v;
  }
  if (tid < 32) *(f32x4*)&w2c[tid * 4] = *(const f32x4*)&W2[hq * 128 + tid * 4];
  __syncthreads();

  const int w = tid >> 6, lane = tid & 63;
  const int i0 = lane & 7, j0 = (lane >> 3) & 7;
  const int hb = w * 16;

  float a00 = 0.f, a01 = 0.f, a10 = 0.f, a11 = 0.f;
#pragma unroll
  for (int it = 0; it < 4; ++it) {
    int h = hb + it * 4;
    f32x4 et0 = *(const f32x4*)&sta[i0][h];
    f32x4 et1 = *(const f32x4*)&sta[i0 + 8][h];
    f32x4 en0 = *(const f32x4*)&seb[j0][h];
    f32x4 en1 = *(const f32x4*)&seb[j0 + 8][h];
    f32x4 w4  = *(const f32x4*)&w2c[h];
#pragma unroll
    for (int u = 0; u < 4; ++u) {
      float r00 = __builtin_amdgcn_rcpf(et0[u] * en0[u] + 1.0f);
      float r01 = __builtin_amdgcn_rcpf(et0[u] * en1[u] + 1.0f);
      float r10 = __builtin_amdgcn_rcpf(et1[u] * en0[u] + 1.0f);
      float r11 = __builtin_amdgcn_rcpf(et1[u] * en1[u] + 1.0f);
      float ww = w4[u];
      a00 += ww * r00; a01 += ww * r01; a10 += ww * r10; a11 += ww * r11;
    }
  }

  red[w][i0][j0]         = a00;
  red[w][i0][j0 + 8]     = a01;
  red[w][i0 + 8][j0]     = a10;
  red[w][i0 + 8][j0 + 8] = a11;
  __syncthreads();

  if (tid < 256) {
    int tl = tid & 15, nl = tid >> 4;
    float s = 0.f;
#pragma unroll
    for (int ww = 0; ww < 8; ++ww) s += red[ww][tl][nl];
    float val = C[CX_OFF + hq] - 2.0f * s;
    atomicAdd(&out[((size_t)(t0 + tl) * NE + (n0 + nl)) * NB + b], val);
  }
}

extern "C" void kernel_launch(void* const* d_in, const int* in_sizes, int n_in,
                              void* d_out, int out_size, void* d_ws, size_t ws_size,
                              hipStream_t stream) {
  (void)in_sizes; (void)n_in; (void)out_size; (void)ws_size;
  const float* targets    = (const float*)d_in[0];
  const float* embeddings = (const float*)d_in[1];
  const float* W1         = (const float*)d_in[2];
  const float* b1         = (const float*)d_in[3];
  const float* W2         = (const float*)d_in[4];
  const float* b2         = (const float*)d_in[5];
  float* out = (float*)d_out;
  float* C   = (float*)d_ws;   // 3072*512 fp32 + 4 floats of Swb_q

  k_gemm<<<dim3(384), dim3(256), 0, stream>>>(targets, embeddings, W1, b1, W2, b2, C, out);
  k_fuse<<<dim3(1152), dim3(512), 0, stream>>>(C, W2, out);
}